// Round 1
// baseline (289.661 us; speedup 1.0000x reference)
//
#include <hip/hip_runtime.h>

#define NB 2
#define NN 2048
#define NC 1024
#define NH 16
#define ND 64

typedef __attribute__((ext_vector_type(4))) float f32x4;
typedef __attribute__((ext_vector_type(8))) short bf16x8;
typedef __attribute__((ext_vector_type(4))) unsigned short us4;

#define MFMA16 __builtin_amdgcn_mfma_f32_16x16x32_bf16

__device__ __forceinline__ unsigned short f2bf(float f) {
    unsigned int u = __builtin_bit_cast(unsigned int, f);
    u = (u + 0x7FFFu + ((u >> 16) & 1u)) >> 16;
    return (unsigned short)u;
}
__device__ __forceinline__ float bf2f(unsigned short h) {
    return __builtin_bit_cast(float, (unsigned int)h << 16);
}

// ---------- bulk fp32 -> bf16 convert ----------
__global__ __launch_bounds__(256) void cvt_bf16(const float* __restrict__ in,
                                                unsigned short* __restrict__ out, int n4) {
    int i = blockIdx.x * blockDim.x + threadIdx.x;
    if (i >= n4) return;
    f32x4 v = reinterpret_cast<const f32x4*>(in)[i];
    us4 o;
    for (int j = 0; j < 4; ++j) o[j] = f2bf(v[j]);
    reinterpret_cast<us4*>(out)[i] = o;
}

// ---------- fp32 -> (hi, lo) bf16 split ----------
__global__ __launch_bounds__(256) void cvt_split(const float* __restrict__ in,
                                                 unsigned short* __restrict__ hi,
                                                 unsigned short* __restrict__ lo, int n4) {
    int i = blockIdx.x * blockDim.x + threadIdx.x;
    if (i >= n4) return;
    f32x4 v = reinterpret_cast<const f32x4*>(in)[i];
    us4 h, l;
    for (int j = 0; j < 4; ++j) {
        unsigned short hb = f2bf(v[j]);
        h[j] = hb;
        l[j] = f2bf(v[j] - bf2f(hb));
    }
    reinterpret_cast<us4*>(hi)[i] = h;
    reinterpret_cast<us4*>(lo)[i] = l;
}

// ---------- fused flash attention ----------
// grid: (N/128, B*H), block: 512 (8 waves x 16 q-rows)
__global__ __launch_bounds__(512) void attn_kernel(const float* __restrict__ q,
                                                   const unsigned short* __restrict__ khi,
                                                   const unsigned short* __restrict__ klo,
                                                   const unsigned short* __restrict__ vb,
                                                   unsigned short* __restrict__ xb) {
    __shared__ unsigned short Kth[32][72];  // [kv][d], pad -> 144B stride (2-way free)
    __shared__ unsigned short Ktl[32][72];
    __shared__ unsigned short Vt[64][40];   // [d][kv] transposed, 80B stride
    __shared__ unsigned short Pl[8][16][40];// per-wave P tile [qrow][kv]

    const int bh = blockIdx.y;
    const int b = bh >> 4, h = bh & 15;
    const int wave = threadIdx.x >> 6;
    const int lane = threadIdx.x & 63;
    const int l15 = lane & 15, lhi = lane >> 4;
    const int qrow0 = blockIdx.x * 128 + wave * 16;

    // Q fragments, split into hi+lo bf16 (A-layout: row=l15, k=lhi*8+j)
    bf16x8 aqh[2], aql[2];
    {
        const float* qp = q + (size_t)(b * NN + qrow0 + l15) * NC + h * ND;
        for (int kc = 0; kc < 2; ++kc) {
            f32x4 x0 = *reinterpret_cast<const f32x4*>(qp + kc * 32 + lhi * 8);
            f32x4 x1 = *reinterpret_cast<const f32x4*>(qp + kc * 32 + lhi * 8 + 4);
            bf16x8 ah, al;
            for (int j = 0; j < 4; ++j) {
                unsigned short hb = f2bf(x0[j]);
                ah[j] = (short)hb; al[j] = (short)f2bf(x0[j] - bf2f(hb));
                hb = f2bf(x1[j]);
                ah[4 + j] = (short)hb; al[4 + j] = (short)f2bf(x1[j] - bf2f(hb));
            }
            aqh[kc] = ah; aql[kc] = al;
        }
    }

    f32x4 acc[4];
    for (int d = 0; d < 4; ++d) acc[d] = (f32x4){0.f, 0.f, 0.f, 0.f};
    float m_r[4], l_r[4];
    for (int v = 0; v < 4; ++v) { m_r[v] = -1e30f; l_r[v] = 0.f; }

    const unsigned short* Khb = khi + (size_t)(b * NH + h) * NN * ND;
    const unsigned short* Klb = klo + (size_t)(b * NH + h) * NN * ND;
    const unsigned short* Vbh = vb + (size_t)(b * NH + h) * NN * ND;

    const int t = threadIdx.x;
    const int kr = t >> 4, kd0 = (t & 15) * 4;  // K staging: coalesced
    const int vr = t & 31, vd0 = (t >> 5) * 4;  // V staging: conflict-free LDS scatter

    for (int kv0 = 0; kv0 < NN; kv0 += 32) {
        __syncthreads();
        {
            us4 kx = *reinterpret_cast<const us4*>(Khb + (size_t)(kv0 + kr) * ND + kd0);
            *reinterpret_cast<us4*>(&Kth[kr][kd0]) = kx;
            us4 lx = *reinterpret_cast<const us4*>(Klb + (size_t)(kv0 + kr) * ND + kd0);
            *reinterpret_cast<us4*>(&Ktl[kr][kd0]) = lx;
            us4 vx = *reinterpret_cast<const us4*>(Vbh + (size_t)(kv0 + vr) * ND + vd0);
            for (int j = 0; j < 4; ++j) Vt[vd0 + j][vr] = vx[j];
        }
        __syncthreads();

        // S = Q K^T, two 16-col blocks, split-bf16 (3 terms, lo*lo dropped)
        f32x4 s[2];
        for (int cb = 0; cb < 2; ++cb) {
            f32x4 sa = (f32x4){0.f, 0.f, 0.f, 0.f};
            for (int kc = 0; kc < 2; ++kc) {
                bf16x8 bh_ = *reinterpret_cast<const bf16x8*>(&Kth[cb * 16 + l15][kc * 32 + lhi * 8]);
                bf16x8 bl_ = *reinterpret_cast<const bf16x8*>(&Ktl[cb * 16 + l15][kc * 32 + lhi * 8]);
                sa = MFMA16(aqh[kc], bh_, sa, 0, 0, 0);
                sa = MFMA16(aql[kc], bh_, sa, 0, 0, 0);
                sa = MFMA16(aqh[kc], bl_, sa, 0, 0, 0);
            }
            s[cb] = sa;
        }

        // online softmax (rows = lhi*4+v, cols = lane&15 within each 16-block)
        float p0[4], p1[4];
        for (int v = 0; v < 4; ++v) {
            float pm = fmaxf(s[0][v], s[1][v]);
            pm = fmaxf(pm, __shfl_xor(pm, 1));
            pm = fmaxf(pm, __shfl_xor(pm, 2));
            pm = fmaxf(pm, __shfl_xor(pm, 4));
            pm = fmaxf(pm, __shfl_xor(pm, 8));
            float mn = fmaxf(m_r[v], pm);
            float al = __expf(m_r[v] - mn);
            m_r[v] = mn;
            p0[v] = __expf(s[0][v] - mn);
            p1[v] = __expf(s[1][v] - mn);
            float rs = p0[v] + p1[v];
            rs += __shfl_xor(rs, 1);
            rs += __shfl_xor(rs, 2);
            rs += __shfl_xor(rs, 4);
            rs += __shfl_xor(rs, 8);
            l_r[v] = l_r[v] * al + rs;
            acc[0][v] *= al; acc[1][v] *= al; acc[2][v] *= al; acc[3][v] *= al;
        }

        // P -> LDS (C-layout) then read back in A-layout
        for (int v = 0; v < 4; ++v) {
            int row = lhi * 4 + v;
            Pl[wave][row][l15] = f2bf(p0[v]);
            Pl[wave][row][16 + l15] = f2bf(p1[v]);
        }
        asm volatile("s_waitcnt lgkmcnt(0)" ::: "memory");
        bf16x8 ap = *reinterpret_cast<const bf16x8*>(&Pl[wave][l15][lhi * 8]);
        for (int db = 0; db < 4; ++db) {
            bf16x8 bv = *reinterpret_cast<const bf16x8*>(&Vt[db * 16 + l15][lhi * 8]);
            acc[db] = MFMA16(ap, bv, acc[db], 0, 0, 0);
        }
    }

    // epilogue: normalize, store bf16 x
    for (int v = 0; v < 4; ++v) {
        float inv = 1.0f / l_r[v];
        int n = qrow0 + lhi * 4 + v;
        unsigned short* xr = xb + (size_t)(b * NN + n) * NC + h * ND;
        for (int db = 0; db < 4; ++db)
            xr[db * 16 + l15] = f2bf(acc[db][v] * inv);
    }
}

// ---------- projection GEMM: out[n][o] = sum_c x[n][c] * W[o][c] + bias[o] ----------
// grid: (4096/64, 1024/64), block 256 (4 waves x 16 rows, 64 cols each)
__global__ __launch_bounds__(256) void proj_kernel(const unsigned short* __restrict__ x,
                                                   const unsigned short* __restrict__ w,
                                                   const float* __restrict__ bias,
                                                   float* __restrict__ out) {
    const int wave = threadIdx.x >> 6, lane = threadIdx.x & 63;
    const int l15 = lane & 15, lhi = lane >> 4;
    const int n0 = blockIdx.x * 64 + wave * 16;
    const int o0 = blockIdx.y * 64;

    f32x4 acc[4];
    for (int c = 0; c < 4; ++c) acc[c] = (f32x4){0.f, 0.f, 0.f, 0.f};

    const unsigned short* xrow = x + (size_t)(n0 + l15) * NC;
    for (int c0 = 0; c0 < NC; c0 += 32) {
        bf16x8 a = *reinterpret_cast<const bf16x8*>(xrow + c0 + lhi * 8);
        for (int cb = 0; cb < 4; ++cb) {
            const unsigned short* wp = w + (size_t)(o0 + cb * 16 + l15) * NC + c0 + lhi * 8;
            bf16x8 bb = *reinterpret_cast<const bf16x8*>(wp);
            acc[cb] = MFMA16(a, bb, acc[cb], 0, 0, 0);
        }
    }
    for (int cb = 0; cb < 4; ++cb)
        for (int v = 0; v < 4; ++v) {
            int n = n0 + lhi * 4 + v;
            int o = o0 + cb * 16 + l15;
            out[(size_t)n * NC + o] = acc[cb][v] + bias[o];
        }
}

extern "C" void kernel_launch(void* const* d_in, const int* in_sizes, int n_in,
                              void* d_out, int out_size, void* d_ws, size_t ws_size,
                              hipStream_t stream) {
    const float* q    = (const float*)d_in[0];
    const float* k    = (const float*)d_in[1];
    const float* v    = (const float*)d_in[2];
    const float* w    = (const float*)d_in[3];
    const float* bias = (const float*)d_in[4];
    float* out = (float*)d_out;

    const size_t KV_ELEMS = (size_t)NB * NH * NN * ND;  // 4,194,304
    const size_t X_ELEMS  = (size_t)NB * NN * NC;       // 4,194,304
    const size_t W_ELEMS  = (size_t)NC * NC;            // 1,048,576

    unsigned short* khi = (unsigned short*)d_ws;
    unsigned short* klo = khi + KV_ELEMS;
    unsigned short* vb  = klo + KV_ELEMS;
    unsigned short* xb  = vb + KV_ELEMS;
    unsigned short* wb  = xb + X_ELEMS;

    cvt_split<<<(int)(KV_ELEMS / 4 / 256), 256, 0, stream>>>(k, khi, klo, (int)(KV_ELEMS / 4));
    cvt_bf16<<<(int)(KV_ELEMS / 4 / 256), 256, 0, stream>>>(v, vb, (int)(KV_ELEMS / 4));
    cvt_bf16<<<(int)(W_ELEMS / 4 / 256), 256, 0, stream>>>(w, wb, (int)(W_ELEMS / 4));

    dim3 ag(NN / 128, NB * NH);
    attn_kernel<<<ag, 512, 0, stream>>>(q, khi, klo, vb, xb);

    dim3 pg((NB * NN) / 64, NC / 64);
    proj_kernel<<<pg, 256, 0, stream>>>(xb, wb, bias, out);
}

// Round 3
// 267.990 us; speedup vs baseline: 1.0809x; 1.0809x over previous
//
#include <hip/hip_runtime.h>

#define NB 2
#define NN 2048
#define NC 1024
#define NH 16
#define ND 64

typedef __attribute__((ext_vector_type(4))) float f32x4;
typedef __attribute__((ext_vector_type(16))) float f32x16;
typedef __attribute__((ext_vector_type(8))) short bf16x8;
typedef __attribute__((ext_vector_type(4))) unsigned short us4;
typedef __attribute__((ext_vector_type(8))) unsigned short us8;
typedef __attribute__((ext_vector_type(4))) unsigned int u32x4;

#define MFMA32 __builtin_amdgcn_mfma_f32_32x32x16_bf16
#define MFMA16 __builtin_amdgcn_mfma_f32_16x16x32_bf16

__device__ __forceinline__ unsigned short f2bf(float f) {
    unsigned int u = __builtin_bit_cast(unsigned int, f);
    u = (u + 0x7FFFu + ((u >> 16) & 1u)) >> 16;
    return (unsigned short)u;
}
__device__ __forceinline__ float bf2f(unsigned short h) {
    return __builtin_bit_cast(float, (unsigned int)h << 16);
}
// pack two f32 -> dword of 2 bf16 (lo in low half)
__device__ __forceinline__ unsigned int pk2(float lo, float hi) {
    return (unsigned int)f2bf(lo) | ((unsigned int)f2bf(hi) << 16);
}

// ---------- bulk fp32 -> bf16 convert ----------
__global__ __launch_bounds__(256) void cvt_bf16(const float* __restrict__ in,
                                                unsigned short* __restrict__ out, int n4) {
    int i = blockIdx.x * blockDim.x + threadIdx.x;
    if (i >= n4) return;
    f32x4 v = reinterpret_cast<const f32x4*>(in)[i];
    us4 o;
    #pragma unroll
    for (int j = 0; j < 4; ++j) o[j] = f2bf(v[j]);
    reinterpret_cast<us4*>(out)[i] = o;
}

// ---------- fp32 -> (hi, lo) bf16 split ----------
__global__ __launch_bounds__(256) void cvt_split(const float* __restrict__ in,
                                                 unsigned short* __restrict__ hi,
                                                 unsigned short* __restrict__ lo, int n4) {
    int i = blockIdx.x * blockDim.x + threadIdx.x;
    if (i >= n4) return;
    f32x4 v = reinterpret_cast<const f32x4*>(in)[i];
    us4 h, l;
    #pragma unroll
    for (int j = 0; j < 4; ++j) {
        unsigned short hb = f2bf(v[j]);
        h[j] = hb;
        l[j] = f2bf(v[j] - bf2f(hb));
    }
    reinterpret_cast<us4*>(hi)[i] = h;
    reinterpret_cast<us4*>(lo)[i] = l;
}

// ---------- V transpose: [b][h][n][d] f32 -> [b][h][d][n] bf16 ----------
// grid (N/64, B*H), block 256
__global__ __launch_bounds__(256) void vt_kernel(const float* __restrict__ v,
                                                 unsigned short* __restrict__ vt) {
    __shared__ unsigned short T[64][72];  // [n][d], pad 8 shorts
    const int bh = blockIdx.y;
    const int n0 = blockIdx.x * 64;
    const int t = threadIdx.x;
    {
        const int nr = t >> 2, d0 = (t & 3) * 16;
        const float* src = v + ((size_t)bh * NN + n0 + nr) * ND + d0;
        #pragma unroll
        for (int c = 0; c < 4; ++c) {
            f32x4 x = *reinterpret_cast<const f32x4*>(src + c * 4);
            us4 r;
            #pragma unroll
            for (int j = 0; j < 4; ++j) r[j] = f2bf(x[j]);
            *reinterpret_cast<us4*>(&T[nr][d0 + c * 4]) = r;
        }
    }
    __syncthreads();
    {
        const int d = t & 63;
        unsigned short* dst = vt + ((size_t)bh * ND + d) * NN + n0;
        #pragma unroll
        for (int pass = 0; pass < 2; ++pass) {
            int nc = (t >> 6) + pass * 4;  // 8-n chunk
            us8 r;
            #pragma unroll
            for (int j = 0; j < 8; ++j) r[j] = T[nc * 8 + j][d];
            *reinterpret_cast<us8*>(dst + nc * 8) = r;
        }
    }
}

// ---------- fused flash attention, swapped-QK^T, 32x32 MFMA, zero LDS ----------
// grid: 512 linear (16 q-tiles x 32 bh), block: 256 (4 waves x 32 q-rows)
__global__ __launch_bounds__(256, 2) void attn_kernel(const float* __restrict__ q,
                                                      const unsigned short* __restrict__ khi,
                                                      const unsigned short* __restrict__ klo,
                                                      const unsigned short* __restrict__ vt,
                                                      unsigned short* __restrict__ xb) {
    // XCD swizzle: pack 64 consecutive blocks (4 heads) per XCD
    const int bid = blockIdx.x;
    const int swz = (bid & 7) * 64 + (bid >> 3);
    const int bh = swz >> 4;   // 0..31
    const int qt = swz & 15;   // q-tile
    const int b = bh >> 4, h = bh & 15;
    const int wave = threadIdx.x >> 6, lane = threadIdx.x & 63;
    const int l31 = lane & 31, hi = lane >> 5;
    const int qrow = qt * 128 + wave * 32 + l31;  // this lane's q row

    // ---- Q row -> split bf16 B-fragments: B[k=ks*16+hi*8+j][col=q] ----
    bf16x8 qh[4], ql[4];
    {
        const float* qp = q + ((size_t)(b * NN + qrow)) * NC + h * ND;
        #pragma unroll
        for (int ks = 0; ks < 4; ++ks) {
            int d = ks * 16 + hi * 8;
            f32x4 x0 = *reinterpret_cast<const f32x4*>(qp + d);
            f32x4 x1 = *reinterpret_cast<const f32x4*>(qp + d + 4);
            bf16x8 ah, al;
            #pragma unroll
            for (int j = 0; j < 4; ++j) {
                unsigned short hb = f2bf(x0[j]);
                ah[j] = (short)hb; al[j] = (short)f2bf(x0[j] - bf2f(hb));
                hb = f2bf(x1[j]);
                ah[4 + j] = (short)hb; al[4 + j] = (short)f2bf(x1[j] - bf2f(hb));
            }
            qh[ks] = ah; ql[ks] = al;
        }
    }

    f32x16 acc0, acc1;
    #pragma unroll
    for (int r = 0; r < 16; ++r) { acc0[r] = 0.f; acc1[r] = 0.f; }
    float m_r = -1e30f, l_r = 0.f;

    const unsigned short* Kh = khi + (size_t)bh * NN * ND;
    const unsigned short* Kl = klo + (size_t)bh * NN * ND;
    const unsigned short* Vb = vt + (size_t)bh * ND * NN;  // [d][n]

    for (int kv0 = 0; kv0 < NN; kv0 += 64) {
        // ---- QK^T (swapped): S^T tile, A = K-frag (row=kv), B = Q-frag (col=q) ----
        f32x16 s[2];
        #pragma unroll
        for (int t = 0; t < 2; ++t) {
            const unsigned short* kbh = Kh + (size_t)(kv0 + t * 32 + l31) * ND + hi * 8;
            const unsigned short* kbl = Kl + (size_t)(kv0 + t * 32 + l31) * ND + hi * 8;
            f32x16 sa;
            #pragma unroll
            for (int r = 0; r < 16; ++r) sa[r] = 0.f;
            #pragma unroll
            for (int ks = 0; ks < 4; ++ks) {
                bf16x8 ah = *reinterpret_cast<const bf16x8*>(kbh + ks * 16);
                bf16x8 al = *reinterpret_cast<const bf16x8*>(kbl + ks * 16);
                sa = MFMA32(ah, qh[ks], sa, 0, 0, 0);
                sa = MFMA32(al, qh[ks], sa, 0, 0, 0);
                sa = MFMA32(ah, ql[ks], sa, 0, 0, 0);
            }
            s[t] = sa;
        }

        // ---- V-fragment prefetch (consumed after softmax) ----
        // A-frag of PV: V^T[row=d=dt*32+l31][k=kv], contiguous in vt
        bf16x8 va[2][2][2];
        #pragma unroll
        for (int dt = 0; dt < 2; ++dt)
            #pragma unroll
            for (int t = 0; t < 2; ++t)
                #pragma unroll
                for (int ks2 = 0; ks2 < 2; ++ks2)
                    va[dt][t][ks2] = *reinterpret_cast<const bf16x8*>(
                        Vb + (size_t)(dt * 32 + l31) * NN + kv0 + t * 32 + ks2 * 16 + hi * 8);

        // ---- lane-local online softmax (lane holds full P-row for q=l31, split with lane^32) ----
        float mx = s[0][0];
        #pragma unroll
        for (int r = 1; r < 16; ++r) mx = fmaxf(mx, s[0][r]);
        #pragma unroll
        for (int r = 0; r < 16; ++r) mx = fmaxf(mx, s[1][r]);
        mx = fmaxf(mx, __shfl_xor(mx, 32));
        float mn = fmaxf(m_r, mx);
        float al = __expf(m_r - mn);
        m_r = mn;
        float p[2][16];
        float rs = 0.f;
        #pragma unroll
        for (int t = 0; t < 2; ++t)
            #pragma unroll
            for (int r = 0; r < 16; ++r) {
                float e = __expf(s[t][r] - mn);
                p[t][r] = e;
                rs += e;
            }
        rs += __shfl_xor(rs, 32);
        l_r = l_r * al + rs;
        acc0 *= al; acc1 *= al;

        // ---- P -> bf16 B-fragments + PV ----
        // lane needs P[q=l31][kv = t*32 + ks2*16 + hi*8 + j]; own regs cover half,
        // partner (lane^32) covers the other half: exchange packed pairs.
        #pragma unroll
        for (int t = 0; t < 2; ++t) {
            #pragma unroll
            for (int ks2 = 0; ks2 < 2; ++ks2) {
                unsigned int sA = pk2(p[t][8 * ks2 + 0], p[t][8 * ks2 + 1]);
                unsigned int sB = pk2(p[t][8 * ks2 + 2], p[t][8 * ks2 + 3]);
                unsigned int sC = pk2(p[t][8 * ks2 + 4], p[t][8 * ks2 + 5]);
                unsigned int sD = pk2(p[t][8 * ks2 + 6], p[t][8 * ks2 + 7]);
                unsigned int snd0 = hi ? sA : sC;
                unsigned int snd1 = hi ? sB : sD;
                unsigned int rcv0 = __shfl_xor(snd0, 32);
                unsigned int rcv1 = __shfl_xor(snd1, 32);
                u32x4 uf;
                uf[0] = hi ? rcv0 : sA;
                uf[1] = hi ? rcv1 : sB;
                uf[2] = hi ? sC : rcv0;
                uf[3] = hi ? sD : rcv1;
                bf16x8 pfrag = __builtin_bit_cast(bf16x8, uf);
                acc0 = MFMA32(va[0][t][ks2], pfrag, acc0, 0, 0, 0);
                acc1 = MFMA32(va[1][t][ks2], pfrag, acc1, 0, 0, 0);
            }
        }
    }

    // ---- epilogue: normalize, redistribute halves, store bf16 x ----
    const float inv = 1.0f / l_r;
    #pragma unroll
    for (int dt = 0; dt < 2; ++dt) {
        const f32x16 a = (dt == 0) ? acc0 : acc1;
        unsigned int P0 = pk2(a[0] * inv, a[1] * inv);
        unsigned int P1 = pk2(a[2] * inv, a[3] * inv);
        unsigned int P2 = pk2(a[4] * inv, a[5] * inv);
        unsigned int P3 = pk2(a[6] * inv, a[7] * inv);
        unsigned int P4 = pk2(a[8] * inv, a[9] * inv);
        unsigned int P5 = pk2(a[10] * inv, a[11] * inv);
        unsigned int P6 = pk2(a[12] * inv, a[13] * inv);
        unsigned int P7 = pk2(a[14] * inv, a[15] * inv);
        unsigned int r0 = __shfl_xor(hi ? P0 : P4, 32);
        unsigned int r1 = __shfl_xor(hi ? P1 : P5, 32);
        unsigned int r2 = __shfl_xor(hi ? P2 : P6, 32);
        unsigned int r3 = __shfl_xor(hi ? P3 : P7, 32);
        // chunk0: d = dt*32 + hi*16 + 0..7 ; chunk1: +8..15
        u32x4 c0, c1;
        c0[0] = hi ? r0 : P0;
        c0[1] = hi ? r1 : P1;
        c0[2] = hi ? P4 : r0;
        c0[3] = hi ? P5 : r1;
        c1[0] = hi ? r2 : P2;
        c1[1] = hi ? r3 : P3;
        c1[2] = hi ? P6 : r2;
        c1[3] = hi ? P7 : r3;
        unsigned short* xr = xb + (size_t)(b * NN + qrow) * NC + h * ND + dt * 32 + hi * 16;
        *reinterpret_cast<u32x4*>(xr) = c0;
        *reinterpret_cast<u32x4*>(xr + 8) = c1;
    }
}

// ---------- projection GEMM: out[n][o] = sum_c x[n][c] * W[o][c] + bias[o] ----------
__global__ __launch_bounds__(256) void proj_kernel(const unsigned short* __restrict__ x,
                                                   const unsigned short* __restrict__ w,
                                                   const float* __restrict__ bias,
                                                   float* __restrict__ out) {
    const int wave = threadIdx.x >> 6, lane = threadIdx.x & 63;
    const int l15 = lane & 15, lhi = lane >> 4;
    const int n0 = blockIdx.x * 64 + wave * 16;
    const int o0 = blockIdx.y * 64;

    f32x4 acc[4];
    #pragma unroll
    for (int c = 0; c < 4; ++c) acc[c] = (f32x4){0.f, 0.f, 0.f, 0.f};

    const unsigned short* xrow = x + (size_t)(n0 + l15) * NC;
    for (int c0 = 0; c0 < NC; c0 += 32) {
        bf16x8 a = *reinterpret_cast<const bf16x8*>(xrow + c0 + lhi * 8);
        #pragma unroll
        for (int cb = 0; cb < 4; ++cb) {
            const unsigned short* wp = w + (size_t)(o0 + cb * 16 + l15) * NC + c0 + lhi * 8;
            bf16x8 bb = *reinterpret_cast<const bf16x8*>(wp);
            acc[cb] = MFMA16(a, bb, acc[cb], 0, 0, 0);
        }
    }
    #pragma unroll
    for (int cb = 0; cb < 4; ++cb)
        #pragma unroll
        for (int v = 0; v < 4; ++v) {
            int n = n0 + lhi * 4 + v;
            int o = o0 + cb * 16 + l15;
            out[(size_t)n * NC + o] = acc[cb][v] + bias[o];
        }
}

extern "C" void kernel_launch(void* const* d_in, const int* in_sizes, int n_in,
                              void* d_out, int out_size, void* d_ws, size_t ws_size,
                              hipStream_t stream) {
    const float* q    = (const float*)d_in[0];
    const float* k    = (const float*)d_in[1];
    const float* v    = (const float*)d_in[2];
    const float* w    = (const float*)d_in[3];
    const float* bias = (const float*)d_in[4];
    float* out = (float*)d_out;

    const size_t KV_ELEMS = (size_t)NB * NH * NN * ND;  // 4,194,304
    const size_t X_ELEMS  = (size_t)NB * NN * NC;       // 4,194,304
    const size_t W_ELEMS  = (size_t)NC * NC;            // 1,048,576

    unsigned short* khi = (unsigned short*)d_ws;
    unsigned short* klo = khi + KV_ELEMS;
    unsigned short* vtb = klo + KV_ELEMS;
    unsigned short* xb  = vtb + KV_ELEMS;
    unsigned short* wb  = xb + X_ELEMS;

    cvt_split<<<(int)(KV_ELEMS / 4 / 256), 256, 0, stream>>>(k, khi, klo, (int)(KV_ELEMS / 4));
    dim3 tg(NN / 64, NB * NH);
    vt_kernel<<<tg, 256, 0, stream>>>(v, vtb);
    cvt_bf16<<<(int)(W_ELEMS / 4 / 256), 256, 0, stream>>>(w, wb, (int)(W_ELEMS / 4));

    attn_kernel<<<512, 256, 0, stream>>>(q, khi, klo, vtb, xb);

    dim3 pg((NB * NN) / 64, NC / 64);
    proj_kernel<<<pg, 256, 0, stream>>>(xb, wb, bias, out);
}